// Round 1
// baseline (796.568 us; speedup 1.0000x reference)
//
#include <hip/hip_runtime.h>
#include <hip/hip_fp16.h>
#include <stdint.h>
#include <math.h>

// MoE MLP block (GPT-OSS style): router top-2 + 8 experts SiLU-GLU, fp16 MFMA.
// v1 design: gather tokens per expert, grouped GEMMs with in-kernel f32->f16
// transpose staging of weights, deterministic combine (no float atomics).

typedef _Float16 f16;
typedef _Float16 f16x8 __attribute__((ext_vector_type(8)));
typedef float f32x4 __attribute__((ext_vector_type(4)));

#define T_TOK 2048
#define DDIM 2880
#define NEXP 8
#define IDIM 2880

#define BM 128
#define BN 96
#define BK 64
#define NKT 45   // 2880/64
#define NNT 30   // 2880/96
#define MAXMT 40 // max total m-tiles: 4096/128 + 8
#define SLOT_CAP 5120

// ---- workspace layout (bytes) ----
#define XH_OFF   0
#define XH_BYTES (T_TOK*DDIM*2)
#define HBUF_OFF (XH_OFF + XH_BYTES)
#define HBUF_BYTES (SLOT_CAP*IDIM*2)
#define YBUF_OFF (HBUF_OFF + HBUF_BYTES)
#define YBUF_BYTES (SLOT_CAP*DDIM*2)
#define META_OFF (YBUF_OFF + YBUF_BYTES)
// meta int32 indices
#define M_COUNT 0
#define M_CUR 8
#define M_OFFS 16      // 9 entries
#define M_NTILES 25
#define M_TILE_E 32    // 64
#define M_TILE_R0 96   // 64
#define M_SLOT_TOK 160            // SLOT_CAP
#define M_SLOT_OF (160+SLOT_CAP)  // 2*T_TOK
#define M_TOK_E (M_SLOT_OF + 2*T_TOK)
#define META_INTS (M_TOK_E + 2*T_TOK)
#define SLOTW_OFF (META_OFF + META_INTS*4)
#define TOKW_OFF  (SLOTW_OFF + SLOT_CAP*4)
#define WS_NEEDED ((size_t)TOKW_OFF + (size_t)T_TOK*2*4)

__device__ __forceinline__ int swz(int row) { return ((row ^ (row >> 3)) & 7) << 4; }

// ---------------- router: f64 logits, top-2, pairwise softmax ----------------
__global__ __launch_bounds__(256) void k_router(
    const float* __restrict__ x, const float* __restrict__ wr,
    int* __restrict__ meta, float* __restrict__ tok_w) {
  const int lane = threadIdx.x & 63;
  const int t = blockIdx.x * 4 + (threadIdx.x >> 6);
  double acc[NEXP];
#pragma unroll
  for (int e = 0; e < NEXP; e++) acc[e] = 0.0;
  for (int d = lane; d < DDIM; d += 64) {
    float xv = x[(size_t)t * DDIM + d];
    float4 w0 = *(const float4*)(wr + (size_t)d * NEXP);
    float4 w1 = *(const float4*)(wr + (size_t)d * NEXP + 4);
    acc[0] += (double)xv * (double)w0.x;
    acc[1] += (double)xv * (double)w0.y;
    acc[2] += (double)xv * (double)w0.z;
    acc[3] += (double)xv * (double)w0.w;
    acc[4] += (double)xv * (double)w1.x;
    acc[5] += (double)xv * (double)w1.y;
    acc[6] += (double)xv * (double)w1.z;
    acc[7] += (double)xv * (double)w1.w;
  }
#pragma unroll
  for (int m = 32; m >= 1; m >>= 1) {
#pragma unroll
    for (int e = 0; e < NEXP; e++) acc[e] += __shfl_xor(acc[e], m, 64);
  }
  if (lane == 0) {
    int e0 = 0;
#pragma unroll
    for (int e = 1; e < NEXP; e++) if (acc[e] > acc[e0]) e0 = e;
    int e1 = (e0 == 0) ? 1 : 0;
#pragma unroll
    for (int e = 0; e < NEXP; e++) if (e != e0 && acc[e] > acc[e1]) e1 = e;
    double w0 = 1.0 / (1.0 + exp(acc[e1] - acc[e0]));
    meta[M_TOK_E + 2*t]     = e0;
    meta[M_TOK_E + 2*t + 1] = e1;
    tok_w[2*t]     = (float)w0;
    tok_w[2*t + 1] = (float)(1.0 - w0);
    atomicAdd(&meta[M_COUNT + e0], 1);
    atomicAdd(&meta[M_COUNT + e1], 1);
  }
}

// ---------------- x f32 -> f16 ----------------
__global__ __launch_bounds__(256) void k_xcvt(const float* __restrict__ x, f16* __restrict__ xh) {
  size_t i = ((size_t)blockIdx.x * 256 + threadIdx.x) * 8;
  float4 a = *(const float4*)(x + i);
  float4 b = *(const float4*)(x + i + 4);
  f16x8 v;
  v[0]=(f16)a.x; v[1]=(f16)a.y; v[2]=(f16)a.z; v[3]=(f16)a.w;
  v[4]=(f16)b.x; v[5]=(f16)b.y; v[6]=(f16)b.z; v[7]=(f16)b.w;
  *(f16x8*)(xh + i) = v;
}

// ---------------- scan: offsets, tile map, pad fill, zero cursors ----------------
__global__ __launch_bounds__(64) void k_scan(int* __restrict__ meta, float* __restrict__ slot_w) {
  __shared__ int s_off[NEXP], s_cnt[NEXP], s_pc[NEXP];
  if (threadIdx.x == 0) {
    int run = 0, nt = 0;
    for (int e = 0; e < NEXP; e++) {
      int c = meta[M_COUNT + e];
      int mt = (c + BM - 1) / BM;
      meta[M_OFFS + e] = run;
      s_off[e] = run; s_cnt[e] = c; s_pc[e] = mt * BM;
      for (int j = 0; j < mt; j++) { meta[M_TILE_E + nt] = e; meta[M_TILE_R0 + nt] = run + j * BM; nt++; }
      run += mt * BM;
      meta[M_CUR + e] = 0;
    }
    meta[M_OFFS + NEXP] = run;
    meta[M_NTILES] = nt;
  }
  __syncthreads();
  for (int e = 0; e < NEXP; e++) {
    for (int i = s_cnt[e] + (int)threadIdx.x; i < s_pc[e]; i += 64) {
      meta[M_SLOT_TOK + s_off[e] + i] = 0;
      slot_w[s_off[e] + i] = 0.0f;
    }
  }
}

// ---------------- scatter tokens into expert slot lists ----------------
__global__ __launch_bounds__(256) void k_scatter(int* __restrict__ meta,
    float* __restrict__ slot_w, const float* __restrict__ tok_w) {
  int t = blockIdx.x * 256 + threadIdx.x;
  if (t >= T_TOK) return;
#pragma unroll
  for (int k = 0; k < 2; k++) {
    int e = meta[M_TOK_E + 2*t + k];
    int pos = atomicAdd(&meta[M_CUR + e], 1);
    int slot = meta[M_OFFS + e] + pos;
    meta[M_SLOT_TOK + slot] = t;
    slot_w[slot] = tok_w[2*t + k];
    meta[M_SLOT_OF + 2*t + k] = slot;
  }
}

// ---------------- GEMM1: h = silu(x@Wg) * (x@Wu), fp16 out ----------------
__global__ __launch_bounds__(256, 2) void k_gemm1(
    const f16* __restrict__ xh, const float* __restrict__ wg, const float* __restrict__ wu,
    f16* __restrict__ hbuf, const int* __restrict__ meta) {
  if ((int)blockIdx.y >= meta[M_NTILES]) return;
  const int e  = meta[M_TILE_E + blockIdx.y];
  const int r0 = meta[M_TILE_R0 + blockIdx.y];
  const int n0 = blockIdx.x * BN;

  __shared__ ushort sA[BM * BK];
  __shared__ ushort sB[2][BN * BK];

  const int tid = threadIdx.x;
  const int lane = tid & 63;
  const int wm = (tid >> 6) >> 1, wn = (tid >> 6) & 1;

  int arow[4], atok[4];
  const int ac8 = tid & 7;
#pragma unroll
  for (int r = 0; r < 4; r++) {
    arow[r] = r * 32 + (tid >> 3);
    atok[r] = meta[M_SLOT_TOK + r0 + arow[r]];
  }
  const int bn0 = (tid % 24) * 4;
  const int bk0 = (tid / 24) * 8;
  const bool bact = tid < 192;

  f32x4 accG[4][3], accU[4][3];
#pragma unroll
  for (int i = 0; i < 4; i++)
#pragma unroll
    for (int j = 0; j < 3; j++) { accG[i][j] = {0.f,0.f,0.f,0.f}; accU[i][j] = {0.f,0.f,0.f,0.f}; }

  for (int kt = 0; kt < NKT; kt++) {
    __syncthreads();
    // stage A (gathered token rows), swizzled [row][k]
#pragma unroll
    for (int r = 0; r < 4; r++) {
      uint4 v = *(const uint4*)(xh + (size_t)atok[r] * DDIM + kt * BK + ac8 * 8);
      *(uint4*)((char*)sA + arow[r] * 128 + ((ac8 * 16) ^ swz(arow[r]))) = v;
    }
    // stage B gate/up: f32 [K,N] -> f16 transposed [n][k], swizzled
    if (bact) {
#pragma unroll
      for (int m = 0; m < 2; m++) {
        const float* w = m ? wu : wg;
        const float* base = w + ((size_t)e * DDIM + (size_t)kt * BK + bk0) * IDIM + n0 + bn0;
        float4 v[8];
#pragma unroll
        for (int j = 0; j < 8; j++) v[j] = *(const float4*)(base + (size_t)j * IDIM);
#pragma unroll
        for (int c = 0; c < 4; c++) {
          f16x8 p;
#pragma unroll
          for (int j = 0; j < 8; j++) {
            float fc = (c==0) ? v[j].x : (c==1) ? v[j].y : (c==2) ? v[j].z : v[j].w;
            p[j] = (f16)fc;
          }
          *(f16x8*)((char*)sB[m] + (bn0 + c) * 128 + ((bk0 * 2) ^ swz(bn0 + c))) = p;
        }
      }
    }
    __syncthreads();
#pragma unroll
    for (int kk = 0; kk < 2; kk++) {
      const int gb = kk * 64 + ((lane >> 4) * 16);
      f16x8 af[4], bg[3], bu[3];
#pragma unroll
      for (int fm = 0; fm < 4; fm++) {
        int row = wm * 64 + fm * 16 + (lane & 15);
        af[fm] = *(const f16x8*)((const char*)sA + row * 128 + (gb ^ swz(row)));
      }
#pragma unroll
      for (int fn = 0; fn < 3; fn++) {
        int row = wn * 48 + fn * 16 + (lane & 15);
        bg[fn] = *(const f16x8*)((const char*)sB[0] + row * 128 + (gb ^ swz(row)));
        bu[fn] = *(const f16x8*)((const char*)sB[1] + row * 128 + (gb ^ swz(row)));
      }
#pragma unroll
      for (int fm = 0; fm < 4; fm++)
#pragma unroll
        for (int fn = 0; fn < 3; fn++) {
          accG[fm][fn] = __builtin_amdgcn_mfma_f32_16x16x32_f16(af[fm], bg[fn], accG[fm][fn], 0, 0, 0);
          accU[fm][fn] = __builtin_amdgcn_mfma_f32_16x16x32_f16(af[fm], bu[fn], accU[fm][fn], 0, 0, 0);
        }
    }
  }
#pragma unroll
  for (int fm = 0; fm < 4; fm++)
#pragma unroll
    for (int fn = 0; fn < 3; fn++)
#pragma unroll
      for (int j = 0; j < 4; j++) {
        int row = wm * 64 + fm * 16 + ((lane >> 4) * 4) + j;
        int col = n0 + wn * 48 + fn * 16 + (lane & 15);
        float g = accG[fm][fn][j], u = accU[fm][fn][j];
        float h = g * u / (1.0f + __expf(-g));
        hbuf[(size_t)(r0 + row) * IDIM + col] = (f16)h;
      }
}

// ---------------- GEMM2: y = (h @ Wd) * slot_weight, fp16 out ----------------
__global__ __launch_bounds__(256, 2) void k_gemm2(
    const f16* __restrict__ hbuf, const float* __restrict__ wd,
    f16* __restrict__ ybuf, const int* __restrict__ meta, const float* __restrict__ slot_w) {
  if ((int)blockIdx.y >= meta[M_NTILES]) return;
  const int e  = meta[M_TILE_E + blockIdx.y];
  const int r0 = meta[M_TILE_R0 + blockIdx.y];
  const int n0 = blockIdx.x * BN;

  __shared__ ushort sA[BM * BK];
  __shared__ ushort sB1[BN * BK];

  const int tid = threadIdx.x;
  const int lane = tid & 63;
  const int wm = (tid >> 6) >> 1, wn = (tid >> 6) & 1;
  const int ac8 = tid & 7;
  int arow[4];
#pragma unroll
  for (int r = 0; r < 4; r++) arow[r] = r * 32 + (tid >> 3);
  const int bn0 = (tid % 24) * 4;
  const int bk0 = (tid / 24) * 8;
  const bool bact = tid < 192;

  f32x4 acc[4][3];
#pragma unroll
  for (int i = 0; i < 4; i++)
#pragma unroll
    for (int j = 0; j < 3; j++) acc[i][j] = {0.f,0.f,0.f,0.f};

  for (int kt = 0; kt < NKT; kt++) {
    __syncthreads();
#pragma unroll
    for (int r = 0; r < 4; r++) {
      uint4 v = *(const uint4*)(hbuf + (size_t)(r0 + arow[r]) * IDIM + kt * BK + ac8 * 8);
      *(uint4*)((char*)sA + arow[r] * 128 + ((ac8 * 16) ^ swz(arow[r]))) = v;
    }
    if (bact) {
      const float* base = wd + ((size_t)e * IDIM + (size_t)kt * BK + bk0) * DDIM + n0 + bn0;
      float4 v[8];
#pragma unroll
      for (int j = 0; j < 8; j++) v[j] = *(const float4*)(base + (size_t)j * DDIM);
#pragma unroll
      for (int c = 0; c < 4; c++) {
        f16x8 p;
#pragma unroll
        for (int j = 0; j < 8; j++) {
          float fc = (c==0) ? v[j].x : (c==1) ? v[j].y : (c==2) ? v[j].z : v[j].w;
          p[j] = (f16)fc;
        }
        *(f16x8*)((char*)sB1 + (bn0 + c) * 128 + ((bk0 * 2) ^ swz(bn0 + c))) = p;
      }
    }
    __syncthreads();
#pragma unroll
    for (int kk = 0; kk < 2; kk++) {
      const int gb = kk * 64 + ((lane >> 4) * 16);
      f16x8 af[4], bf[3];
#pragma unroll
      for (int fm = 0; fm < 4; fm++) {
        int row = wm * 64 + fm * 16 + (lane & 15);
        af[fm] = *(const f16x8*)((const char*)sA + row * 128 + (gb ^ swz(row)));
      }
#pragma unroll
      for (int fn = 0; fn < 3; fn++) {
        int row = wn * 48 + fn * 16 + (lane & 15);
        bf[fn] = *(const f16x8*)((const char*)sB1 + row * 128 + (gb ^ swz(row)));
      }
#pragma unroll
      for (int fm = 0; fm < 4; fm++)
#pragma unroll
        for (int fn = 0; fn < 3; fn++)
          acc[fm][fn] = __builtin_amdgcn_mfma_f32_16x16x32_f16(af[fm], bf[fn], acc[fm][fn], 0, 0, 0);
    }
  }
#pragma unroll
  for (int fm = 0; fm < 4; fm++)
#pragma unroll
    for (int fn = 0; fn < 3; fn++)
#pragma unroll
      for (int j = 0; j < 4; j++) {
        int row = wm * 64 + fm * 16 + ((lane >> 4) * 4) + j;
        int col = n0 + wn * 48 + fn * 16 + (lane & 15);
        int slot = r0 + row;
        float wv = slot_w[slot];
        ybuf[(size_t)slot * DDIM + col] = (f16)(acc[fm][fn][j] * wv);
      }
}

// ---------------- combine: out[t] = y[slot0] + y[slot1] ----------------
__global__ __launch_bounds__(256) void k_combine(const f16* __restrict__ ybuf,
    const int* __restrict__ meta, float* __restrict__ out) {
  size_t idx = (size_t)blockIdx.x * 256 + threadIdx.x;
  int t = (int)(idx / (DDIM/8));
  int c = (int)(idx % (DDIM/8));
  int s0 = meta[M_SLOT_OF + 2*t];
  int s1 = meta[M_SLOT_OF + 2*t + 1];
  f16x8 a = *(const f16x8*)(ybuf + (size_t)s0 * DDIM + c*8);
  f16x8 b = *(const f16x8*)(ybuf + (size_t)s1 * DDIM + c*8);
  float4 o0, o1;
  o0.x = (float)a[0] + (float)b[0];
  o0.y = (float)a[1] + (float)b[1];
  o0.z = (float)a[2] + (float)b[2];
  o0.w = (float)a[3] + (float)b[3];
  o1.x = (float)a[4] + (float)b[4];
  o1.y = (float)a[5] + (float)b[5];
  o1.z = (float)a[6] + (float)b[6];
  o1.w = (float)a[7] + (float)b[7];
  float* op = out + (size_t)t * DDIM + c*8;
  *(float4*)op = o0;
  *(float4*)(op + 4) = o1;
}

extern "C" void kernel_launch(void* const* d_in, const int* in_sizes, int n_in,
                              void* d_out, int out_size, void* d_ws, size_t ws_size,
                              hipStream_t stream) {
  const float* x  = (const float*)d_in[0];
  const float* wr = (const float*)d_in[1];
  const float* wg = (const float*)d_in[2];
  const float* wu = (const float*)d_in[3];
  const float* wd = (const float*)d_in[4];
  float* out = (float*)d_out;
  char* ws = (char*)d_ws;
  if (ws_size < WS_NEEDED) return;  // fail loudly (output stays poisoned)

  f16* xh    = (f16*)(ws + XH_OFF);
  f16* hbuf  = (f16*)(ws + HBUF_OFF);
  f16* ybuf  = (f16*)(ws + YBUF_OFF);
  int* meta  = (int*)(ws + META_OFF);
  float* slot_w = (float*)(ws + SLOTW_OFF);
  float* tok_w  = (float*)(ws + TOKW_OFF);

  hipMemsetAsync(meta + M_COUNT, 0, NEXP * sizeof(int), stream);
  k_router<<<T_TOK/4, 256, 0, stream>>>(x, wr, meta, tok_w);
  k_xcvt<<<(T_TOK*DDIM/8 + 255)/256, 256, 0, stream>>>(x, xh);
  k_scan<<<1, 64, 0, stream>>>(meta, slot_w);
  k_scatter<<<(T_TOK + 255)/256, 256, 0, stream>>>(meta, slot_w, tok_w);
  k_gemm1<<<dim3(NNT, MAXMT), 256, 0, stream>>>(xh, wg, wu, hbuf, meta);
  k_gemm2<<<dim3(NNT, MAXMT), 256, 0, stream>>>(hbuf, wd, ybuf, meta, slot_w);
  k_combine<<<(T_TOK*DDIM/8 + 255)/256, 256, 0, stream>>>(ybuf, meta, out);
}

// Round 2
// 619.739 us; speedup vs baseline: 1.2853x; 1.2853x over previous
//
#include <hip/hip_runtime.h>
#include <hip/hip_fp16.h>
#include <stdint.h>
#include <math.h>

// MoE MLP block: router top-2 + 8 experts SiLU-GLU, fp16 MFMA.
// v2: software-pipelined grouped GEMMs (reg-prefetch B, global_load_lds A with
// pre-swizzled source), XCD-chunked grid for weight L2 reuse.

typedef _Float16 f16;
typedef _Float16 f16x8 __attribute__((ext_vector_type(8)));
typedef float f32x4 __attribute__((ext_vector_type(4)));

#define T_TOK 2048
#define DDIM 2880
#define NEXP 8
#define IDIM 2880

#define BM 128
#define BN 96
#define BK 64
#define NKT 45   // 2880/64
#define NNT 30   // 2880/96
#define MAXMT 40 // max total m-tiles: 4096/128 + 8
#define NBLK (NNT*MAXMT)
#define SLOT_CAP 5120

// ---- workspace layout (bytes) ----
#define XH_OFF   0
#define XH_BYTES (T_TOK*DDIM*2)
#define HBUF_OFF (XH_OFF + XH_BYTES)
#define HBUF_BYTES (SLOT_CAP*IDIM*2)
#define YBUF_OFF (HBUF_OFF + HBUF_BYTES)
#define YBUF_BYTES (SLOT_CAP*DDIM*2)
#define META_OFF (YBUF_OFF + YBUF_BYTES)
// meta int32 indices
#define M_COUNT 0
#define M_CUR 8
#define M_OFFS 16      // 9 entries
#define M_NTILES 25
#define M_TILE_E 32    // 64
#define M_TILE_R0 96   // 64
#define M_SLOT_TOK 160            // SLOT_CAP
#define M_SLOT_OF (160+SLOT_CAP)  // 2*T_TOK
#define M_TOK_E (M_SLOT_OF + 2*T_TOK)
#define META_INTS (M_TOK_E + 2*T_TOK)
#define SLOTW_OFF (META_OFF + META_INTS*4)
#define TOKW_OFF  (SLOTW_OFF + SLOT_CAP*4)
#define WS_NEEDED ((size_t)TOKW_OFF + (size_t)T_TOK*2*4)

__device__ __forceinline__ int swz(int row) { return ((row ^ (row >> 3)) & 7) << 4; }

__device__ __forceinline__ void gload_lds16(const void* gp, void* lp) {
  __builtin_amdgcn_global_load_lds(
      (const __attribute__((address_space(1))) uint32_t*)gp,
      (__attribute__((address_space(3))) uint32_t*)lp,
      16, 0, 0);
}

// ---------------- router: f64 logits, top-2, pairwise softmax ----------------
__global__ __launch_bounds__(256) void k_router(
    const float* __restrict__ x, const float* __restrict__ wr,
    int* __restrict__ meta, float* __restrict__ tok_w) {
  const int lane = threadIdx.x & 63;
  const int t = blockIdx.x * 4 + (threadIdx.x >> 6);
  double acc[NEXP];
#pragma unroll
  for (int e = 0; e < NEXP; e++) acc[e] = 0.0;
  for (int d = lane; d < DDIM; d += 64) {
    float xv = x[(size_t)t * DDIM + d];
    float4 w0 = *(const float4*)(wr + (size_t)d * NEXP);
    float4 w1 = *(const float4*)(wr + (size_t)d * NEXP + 4);
    acc[0] += (double)xv * (double)w0.x;
    acc[1] += (double)xv * (double)w0.y;
    acc[2] += (double)xv * (double)w0.z;
    acc[3] += (double)xv * (double)w0.w;
    acc[4] += (double)xv * (double)w1.x;
    acc[5] += (double)xv * (double)w1.y;
    acc[6] += (double)xv * (double)w1.z;
    acc[7] += (double)xv * (double)w1.w;
  }
#pragma unroll
  for (int m = 32; m >= 1; m >>= 1) {
#pragma unroll
    for (int e = 0; e < NEXP; e++) acc[e] += __shfl_xor(acc[e], m, 64);
  }
  if (lane == 0) {
    int e0 = 0;
#pragma unroll
    for (int e = 1; e < NEXP; e++) if (acc[e] > acc[e0]) e0 = e;
    int e1 = (e0 == 0) ? 1 : 0;
#pragma unroll
    for (int e = 0; e < NEXP; e++) if (e != e0 && acc[e] > acc[e1]) e1 = e;
    double w0 = 1.0 / (1.0 + exp(acc[e1] - acc[e0]));
    meta[M_TOK_E + 2*t]     = e0;
    meta[M_TOK_E + 2*t + 1] = e1;
    tok_w[2*t]     = (float)w0;
    tok_w[2*t + 1] = (float)(1.0 - w0);
    atomicAdd(&meta[M_COUNT + e0], 1);
    atomicAdd(&meta[M_COUNT + e1], 1);
  }
}

// ---------------- x f32 -> f16 ----------------
__global__ __launch_bounds__(256) void k_xcvt(const float* __restrict__ x, f16* __restrict__ xh) {
  size_t i = ((size_t)blockIdx.x * 256 + threadIdx.x) * 8;
  float4 a = *(const float4*)(x + i);
  float4 b = *(const float4*)(x + i + 4);
  f16x8 v;
  v[0]=(f16)a.x; v[1]=(f16)a.y; v[2]=(f16)a.z; v[3]=(f16)a.w;
  v[4]=(f16)b.x; v[5]=(f16)b.y; v[6]=(f16)b.z; v[7]=(f16)b.w;
  *(f16x8*)(xh + i) = v;
}

// ---------------- scan: offsets, tile map, pad fill, zero cursors ----------------
__global__ __launch_bounds__(64) void k_scan(int* __restrict__ meta, float* __restrict__ slot_w) {
  __shared__ int s_off[NEXP], s_cnt[NEXP], s_pc[NEXP];
  if (threadIdx.x == 0) {
    int run = 0, nt = 0;
    for (int e = 0; e < NEXP; e++) {
      int c = meta[M_COUNT + e];
      int mt = (c + BM - 1) / BM;
      meta[M_OFFS + e] = run;
      s_off[e] = run; s_cnt[e] = c; s_pc[e] = mt * BM;
      for (int j = 0; j < mt; j++) { meta[M_TILE_E + nt] = e; meta[M_TILE_R0 + nt] = run + j * BM; nt++; }
      run += mt * BM;
      meta[M_CUR + e] = 0;
    }
    meta[M_OFFS + NEXP] = run;
    meta[M_NTILES] = nt;
  }
  __syncthreads();
  for (int e = 0; e < NEXP; e++) {
    for (int i = s_cnt[e] + (int)threadIdx.x; i < s_pc[e]; i += 64) {
      meta[M_SLOT_TOK + s_off[e] + i] = 0;
      slot_w[s_off[e] + i] = 0.0f;
    }
  }
}

// ---------------- scatter tokens into expert slot lists ----------------
__global__ __launch_bounds__(256) void k_scatter(int* __restrict__ meta,
    float* __restrict__ slot_w, const float* __restrict__ tok_w) {
  int t = blockIdx.x * 256 + threadIdx.x;
  if (t >= T_TOK) return;
#pragma unroll
  for (int k = 0; k < 2; k++) {
    int e = meta[M_TOK_E + 2*t + k];
    int pos = atomicAdd(&meta[M_CUR + e], 1);
    int slot = meta[M_OFFS + e] + pos;
    meta[M_SLOT_TOK + slot] = t;
    slot_w[slot] = tok_w[2*t + k];
    meta[M_SLOT_OF + 2*t + k] = slot;
  }
}

// ---------------- GEMM1: h = silu(x@Wg) * (x@Wu), fp16 out, pipelined ----------------
__global__ __launch_bounds__(256, 2) void k_gemm1(
    const f16* __restrict__ xh, const float* __restrict__ wg, const float* __restrict__ wu,
    f16* __restrict__ hbuf, const int* __restrict__ meta) {
  // XCD-chunked swizzle: m-tile fastest so same-(e,n) blocks share an XCD's L2
  const int id = blockIdx.x;
  const int sid = (id & 7) * (NBLK / 8) + (id >> 3);
  const int mt = sid % MAXMT;
  const int nb = sid / MAXMT;
  if (mt >= meta[M_NTILES]) return;
  const int e  = meta[M_TILE_E + mt];
  const int r0 = meta[M_TILE_R0 + mt];
  const int n0 = nb * BN;

  __shared__ ushort sA[2][BM * BK];   // 2 x 16 KB, double-buffered (DMA target)
  __shared__ ushort sB[2][BN * BK];   // gate/up, 2 x 12 KB, single-buffered

  const int tid = threadIdx.x;
  const int lane = tid & 63;
  const int w = tid >> 6;
  const int wm = w >> 1, wn = w & 1;

  // A staging via global_load_lds: 16 segments of 1KB (8 rows each).
  // LDS linear dest; global source pre-swizzled so reads can use swz().
  const char* a_gbase[4];
  int a_loff[4];
#pragma unroll
  for (int i = 0; i < 4; i++) {
    int seg = w * 4 + i;
    int row = seg * 8 + (lane >> 3);
    int colb = ((lane & 7) * 16) ^ swz(row);
    int tok = meta[M_SLOT_TOK + r0 + row];
    a_gbase[i] = (const char*)(xh + (size_t)tok * DDIM) + colb;
    a_loff[i] = seg * 1024;
  }

  // B staging: 192 threads, 8 strided float4 per matrix
  const int bn0 = (tid % 24) * 4;
  const int bk0 = (tid / 24) * 8;
  const bool bact = tid < 192;
  const float* bgbase = wg + ((size_t)e * DDIM + bk0) * IDIM + n0 + bn0;
  const float* bubase = wu + ((size_t)e * DDIM + bk0) * IDIM + n0 + bn0;

  float4 vB[2][8];

  f32x4 accG[4][3], accU[4][3];
#pragma unroll
  for (int i = 0; i < 4; i++)
#pragma unroll
    for (int j = 0; j < 3; j++) { accG[i][j] = {0.f,0.f,0.f,0.f}; accU[i][j] = {0.f,0.f,0.f,0.f}; }

  // prologue: issue tile 0
#pragma unroll
  for (int i = 0; i < 4; i++) gload_lds16(a_gbase[i], (char*)sA[0] + a_loff[i]);
  if (bact) {
#pragma unroll
    for (int j = 0; j < 8; j++) vB[0][j] = *(const float4*)(bgbase + (size_t)j * IDIM);
#pragma unroll
    for (int j = 0; j < 8; j++) vB[1][j] = *(const float4*)(bubase + (size_t)j * IDIM);
  }

  for (int kt = 0; kt < NKT; kt++) {
    const int cur = kt & 1;
    __syncthreads();   // (a) drains prefetches; sB/sA[cur^1] safe to overwrite
    if (bact) {
#pragma unroll
      for (int m = 0; m < 2; m++)
#pragma unroll
        for (int c = 0; c < 4; c++) {
          f16x8 p;
#pragma unroll
          for (int j = 0; j < 8; j++) {
            float fc = (c==0) ? vB[m][j].x : (c==1) ? vB[m][j].y : (c==2) ? vB[m][j].z : vB[m][j].w;
            p[j] = (f16)fc;
          }
          *(f16x8*)((char*)sB[m] + (bn0 + c) * 128 + ((bk0 * 2) ^ swz(bn0 + c))) = p;
        }
    }
    __syncthreads();   // (b) sB(kt) visible; no vmem outstanding here
    if (kt + 1 < NKT) {
      // prefetch tile kt+1: flies during MFMA phase
#pragma unroll
      for (int i = 0; i < 4; i++)
        gload_lds16(a_gbase[i] + (kt + 1) * 128, (char*)sA[cur ^ 1] + a_loff[i]);
      if (bact) {
        const float* bg = bgbase + (size_t)(kt + 1) * BK * IDIM;
        const float* bu = bubase + (size_t)(kt + 1) * BK * IDIM;
#pragma unroll
        for (int j = 0; j < 8; j++) vB[0][j] = *(const float4*)(bg + (size_t)j * IDIM);
#pragma unroll
        for (int j = 0; j < 8; j++) vB[1][j] = *(const float4*)(bu + (size_t)j * IDIM);
      }
    }
#pragma unroll
    for (int kk = 0; kk < 2; kk++) {
      const int gb = kk * 64 + ((lane >> 4) * 16);
      f16x8 af[4], bg[3], bu[3];
#pragma unroll
      for (int fm = 0; fm < 4; fm++) {
        int row = wm * 64 + fm * 16 + (lane & 15);
        af[fm] = *(const f16x8*)((const char*)sA[cur] + row * 128 + (gb ^ swz(row)));
      }
#pragma unroll
      for (int fn = 0; fn < 3; fn++) {
        int row = wn * 48 + fn * 16 + (lane & 15);
        bg[fn] = *(const f16x8*)((const char*)sB[0] + row * 128 + (gb ^ swz(row)));
        bu[fn] = *(const f16x8*)((const char*)sB[1] + row * 128 + (gb ^ swz(row)));
      }
#pragma unroll
      for (int fm = 0; fm < 4; fm++)
#pragma unroll
        for (int fn = 0; fn < 3; fn++) {
          accG[fm][fn] = __builtin_amdgcn_mfma_f32_16x16x32_f16(af[fm], bg[fn], accG[fm][fn], 0, 0, 0);
          accU[fm][fn] = __builtin_amdgcn_mfma_f32_16x16x32_f16(af[fm], bu[fn], accU[fm][fn], 0, 0, 0);
        }
    }
  }
#pragma unroll
  for (int fm = 0; fm < 4; fm++)
#pragma unroll
    for (int fn = 0; fn < 3; fn++)
#pragma unroll
      for (int j = 0; j < 4; j++) {
        int row = wm * 64 + fm * 16 + ((lane >> 4) * 4) + j;
        int col = n0 + wn * 48 + fn * 16 + (lane & 15);
        float g = accG[fm][fn][j], u = accU[fm][fn][j];
        float h = g * u / (1.0f + __expf(-g));
        hbuf[(size_t)(r0 + row) * IDIM + col] = (f16)h;
      }
}

// ---------------- GEMM2: y = (h @ Wd) * slot_weight, fp16 out, pipelined ----------------
__global__ __launch_bounds__(256, 3) void k_gemm2(
    const f16* __restrict__ hbuf, const float* __restrict__ wd,
    f16* __restrict__ ybuf, const int* __restrict__ meta, const float* __restrict__ slot_w) {
  const int id = blockIdx.x;
  const int sid = (id & 7) * (NBLK / 8) + (id >> 3);
  const int mt = sid % MAXMT;
  const int nb = sid / MAXMT;
  if (mt >= meta[M_NTILES]) return;
  const int e  = meta[M_TILE_E + mt];
  const int r0 = meta[M_TILE_R0 + mt];
  const int n0 = nb * BN;

  __shared__ ushort sA[2][BM * BK];
  __shared__ ushort sB1[BN * BK];

  const int tid = threadIdx.x;
  const int lane = tid & 63;
  const int w = tid >> 6;
  const int wm = w >> 1, wn = w & 1;

  const char* a_gbase[4];
  int a_loff[4];
#pragma unroll
  for (int i = 0; i < 4; i++) {
    int seg = w * 4 + i;
    int row = seg * 8 + (lane >> 3);
    int colb = ((lane & 7) * 16) ^ swz(row);
    a_gbase[i] = (const char*)(hbuf + (size_t)(r0 + row) * IDIM) + colb;
    a_loff[i] = seg * 1024;
  }

  const int bn0 = (tid % 24) * 4;
  const int bk0 = (tid / 24) * 8;
  const bool bact = tid < 192;
  const float* bdbase = wd + ((size_t)e * IDIM + bk0) * DDIM + n0 + bn0;

  float4 vB[8];

  f32x4 acc[4][3];
#pragma unroll
  for (int i = 0; i < 4; i++)
#pragma unroll
    for (int j = 0; j < 3; j++) acc[i][j] = {0.f,0.f,0.f,0.f};

#pragma unroll
  for (int i = 0; i < 4; i++) gload_lds16(a_gbase[i], (char*)sA[0] + a_loff[i]);
  if (bact) {
#pragma unroll
    for (int j = 0; j < 8; j++) vB[j] = *(const float4*)(bdbase + (size_t)j * DDIM);
  }

  for (int kt = 0; kt < NKT; kt++) {
    const int cur = kt & 1;
    __syncthreads();   // (a)
    if (bact) {
#pragma unroll
      for (int c = 0; c < 4; c++) {
        f16x8 p;
#pragma unroll
        for (int j = 0; j < 8; j++) {
          float fc = (c==0) ? vB[j].x : (c==1) ? vB[j].y : (c==2) ? vB[j].z : vB[j].w;
          p[j] = (f16)fc;
        }
        *(f16x8*)((char*)sB1 + (bn0 + c) * 128 + ((bk0 * 2) ^ swz(bn0 + c))) = p;
      }
    }
    __syncthreads();   // (b)
    if (kt + 1 < NKT) {
#pragma unroll
      for (int i = 0; i < 4; i++)
        gload_lds16(a_gbase[i] + (kt + 1) * 128, (char*)sA[cur ^ 1] + a_loff[i]);
      if (bact) {
        const float* bd = bdbase + (size_t)(kt + 1) * BK * DDIM;
#pragma unroll
        for (int j = 0; j < 8; j++) vB[j] = *(const float4*)(bd + (size_t)j * DDIM);
      }
    }
#pragma unroll
    for (int kk = 0; kk < 2; kk++) {
      const int gb = kk * 64 + ((lane >> 4) * 16);
      f16x8 af[4], bf[3];
#pragma unroll
      for (int fm = 0; fm < 4; fm++) {
        int row = wm * 64 + fm * 16 + (lane & 15);
        af[fm] = *(const f16x8*)((const char*)sA[cur] + row * 128 + (gb ^ swz(row)));
      }
#pragma unroll
      for (int fn = 0; fn < 3; fn++) {
        int row = wn * 48 + fn * 16 + (lane & 15);
        bf[fn] = *(const f16x8*)((const char*)sB1 + row * 128 + (gb ^ swz(row)));
      }
#pragma unroll
      for (int fm = 0; fm < 4; fm++)
#pragma unroll
        for (int fn = 0; fn < 3; fn++)
          acc[fm][fn] = __builtin_amdgcn_mfma_f32_16x16x32_f16(af[fm], bf[fn], acc[fm][fn], 0, 0, 0);
    }
  }
#pragma unroll
  for (int fm = 0; fm < 4; fm++)
#pragma unroll
    for (int fn = 0; fn < 3; fn++)
#pragma unroll
      for (int j = 0; j < 4; j++) {
        int row = wm * 64 + fm * 16 + ((lane >> 4) * 4) + j;
        int col = n0 + wn * 48 + fn * 16 + (lane & 15);
        int slot = r0 + row;
        float wv = slot_w[slot];
        ybuf[(size_t)slot * DDIM + col] = (f16)(acc[fm][fn][j] * wv);
      }
}

// ---------------- combine: out[t] = y[slot0] + y[slot1] ----------------
__global__ __launch_bounds__(256) void k_combine(const f16* __restrict__ ybuf,
    const int* __restrict__ meta, float* __restrict__ out) {
  size_t idx = (size_t)blockIdx.x * 256 + threadIdx.x;
  int t = (int)(idx / (DDIM/8));
  int c = (int)(idx % (DDIM/8));
  int s0 = meta[M_SLOT_OF + 2*t];
  int s1 = meta[M_SLOT_OF + 2*t + 1];
  f16x8 a = *(const f16x8*)(ybuf + (size_t)s0 * DDIM + c*8);
  f16x8 b = *(const f16x8*)(ybuf + (size_t)s1 * DDIM + c*8);
  float4 o0, o1;
  o0.x = (float)a[0] + (float)b[0];
  o0.y = (float)a[1] + (float)b[1];
  o0.z = (float)a[2] + (float)b[2];
  o0.w = (float)a[3] + (float)b[3];
  o1.x = (float)a[4] + (float)b[4];
  o1.y = (float)a[5] + (float)b[5];
  o1.z = (float)a[6] + (float)b[6];
  o1.w = (float)a[7] + (float)b[7];
  float* op = out + (size_t)t * DDIM + c*8;
  *(float4*)op = o0;
  *(float4*)(op + 4) = o1;
}

extern "C" void kernel_launch(void* const* d_in, const int* in_sizes, int n_in,
                              void* d_out, int out_size, void* d_ws, size_t ws_size,
                              hipStream_t stream) {
  const float* x  = (const float*)d_in[0];
  const float* wr = (const float*)d_in[1];
  const float* wg = (const float*)d_in[2];
  const float* wu = (const float*)d_in[3];
  const float* wd = (const float*)d_in[4];
  float* out = (float*)d_out;
  char* ws = (char*)d_ws;
  if (ws_size < WS_NEEDED) return;  // fail loudly (output stays poisoned)

  f16* xh    = (f16*)(ws + XH_OFF);
  f16* hbuf  = (f16*)(ws + HBUF_OFF);
  f16* ybuf  = (f16*)(ws + YBUF_OFF);
  int* meta  = (int*)(ws + META_OFF);
  float* slot_w = (float*)(ws + SLOTW_OFF);
  float* tok_w  = (float*)(ws + TOKW_OFF);

  hipMemsetAsync(meta + M_COUNT, 0, NEXP * sizeof(int), stream);
  k_router<<<T_TOK/4, 256, 0, stream>>>(x, wr, meta, tok_w);
  k_xcvt<<<(T_TOK*DDIM/8 + 255)/256, 256, 0, stream>>>(x, xh);
  k_scan<<<1, 64, 0, stream>>>(meta, slot_w);
  k_scatter<<<(T_TOK + 255)/256, 256, 0, stream>>>(meta, slot_w, tok_w);
  k_gemm1<<<NBLK, 256, 0, stream>>>(xh, wg, wu, hbuf, meta);
  k_gemm2<<<NBLK, 256, 0, stream>>>(hbuf, wd, ybuf, meta, slot_w);
  k_combine<<<(T_TOK*DDIM/8 + 255)/256, 256, 0, stream>>>(ybuf, meta, out);
}